// Round 1
// baseline (313.259 us; speedup 1.0000x reference)
//
#include <hip/hip_runtime.h>
#include <hip/hip_bf16.h>

constexpr int N_NODES = 50000;
constexpr int DIN     = 256;
constexpr int C_OUT   = 128;
constexpr int E_EDGES = 800000;
constexpr int ET      = E_EDGES + N_NODES;   // with self-loops
constexpr float NEG_SLOPE = 0.2f;

// ---------------------------------------------------------------------------
// K1: h = x @ W   (fp32, 64x128 tile, BK=64)
// ---------------------------------------------------------------------------
__global__ __launch_bounds__(256) void gemm_kernel(const float* __restrict__ x,
                                                   const float* __restrict__ W,
                                                   float* __restrict__ h) {
    __shared__ float xs[64][65];    // transposed: xs[k][row]  (+1 pad)
    __shared__ float wsd[64][128];  // wsd[k][col]
    const int t = threadIdx.x;
    const int row0 = blockIdx.x * 64;
    const int ry = t & 15;   // row group: rows ry*4..ry*4+3
    const int cx = t >> 4;   // col group: cols cx*8..cx*8+7
    float acc[4][8] = {};

    for (int k0 = 0; k0 < DIN; k0 += 64) {
        // stage x tile (transposed into LDS)
        {
            const int lr = t >> 4;          // 0..15
            const int lk = (t & 15) * 4;    // 0,4,...,60
            #pragma unroll
            for (int i = 0; i < 4; i++) {
                const int row = row0 + lr + i * 16;
                float4 v = make_float4(0.f, 0.f, 0.f, 0.f);
                if (row < N_NODES)
                    v = *(const float4*)(x + (size_t)row * DIN + k0 + lk);
                xs[lk + 0][lr + i * 16] = v.x;
                xs[lk + 1][lr + i * 16] = v.y;
                xs[lk + 2][lr + i * 16] = v.z;
                xs[lk + 3][lr + i * 16] = v.w;
            }
        }
        // stage W tile
        {
            const int lc = (t & 31) * 4;    // col
            const int lk = t >> 5;          // 0..7
            #pragma unroll
            for (int i = 0; i < 8; i++) {
                const int k = lk + i * 8;
                *(float4*)&wsd[k][lc] = *(const float4*)(W + (size_t)(k0 + k) * C_OUT + lc);
            }
        }
        __syncthreads();
        #pragma unroll 4
        for (int k = 0; k < 64; k++) {
            const float4 a  = *(const float4*)&xs[k][ry * 4];
            const float4 b0 = *(const float4*)&wsd[k][cx * 8];
            const float4 b1 = *(const float4*)&wsd[k][cx * 8 + 4];
            const float av[4] = {a.x, a.y, a.z, a.w};
            const float bv[8] = {b0.x, b0.y, b0.z, b0.w, b1.x, b1.y, b1.z, b1.w};
            #pragma unroll
            for (int r = 0; r < 4; r++)
                #pragma unroll
                for (int c = 0; c < 8; c++)
                    acc[r][c] += av[r] * bv[c];
        }
        __syncthreads();
    }
    #pragma unroll
    for (int r = 0; r < 4; r++) {
        const int row = row0 + ry * 4 + r;
        if (row < N_NODES) {
            float4 o0 = make_float4(acc[r][0], acc[r][1], acc[r][2], acc[r][3]);
            float4 o1 = make_float4(acc[r][4], acc[r][5], acc[r][6], acc[r][7]);
            *(float4*)(h + (size_t)row * C_OUT + cx * 8)     = o0;
            *(float4*)(h + (size_t)row * C_OUT + cx * 8 + 4) = o1;
        }
    }
}

// ---------------------------------------------------------------------------
// K2: per-node attention scalars  s_dst = h . att[0:128], s_src = h . att[128:256]
// one wave per node
// ---------------------------------------------------------------------------
__global__ __launch_bounds__(256) void snode_kernel(const float* __restrict__ h,
                                                    const float* __restrict__ att,
                                                    float* __restrict__ s_dst,
                                                    float* __restrict__ s_src) {
    const int node = (blockIdx.x * 256 + threadIdx.x) >> 6;
    const int lane = threadIdx.x & 63;
    if (node >= N_NODES) return;
    const float2 hv = *(const float2*)(h + (size_t)node * C_OUT + lane * 2);
    const float2 ad = *(const float2*)(att + lane * 2);
    const float2 as = *(const float2*)(att + C_OUT + lane * 2);
    float pd = hv.x * ad.x + hv.y * ad.y;
    float ps = hv.x * as.x + hv.y * as.y;
    #pragma unroll
    for (int off = 32; off >= 1; off >>= 1) {
        pd += __shfl_xor(pd, off);
        ps += __shfl_xor(ps, off);
    }
    if (lane == 0) { s_dst[node] = pd; s_src[node] = ps; }
}

// ---------------------------------------------------------------------------
// K3: count edges per destination (self-loops implicit for e >= E)
// ---------------------------------------------------------------------------
__global__ void count_kernel(const int* __restrict__ ei, int* __restrict__ counts) {
    const int e = blockIdx.x * 256 + threadIdx.x;
    if (e >= ET) return;
    const int d = (e < E_EDGES) ? ei[E_EDGES + e] : (e - E_EDGES);
    atomicAdd(&counts[d], 1);
}

// ---------------------------------------------------------------------------
// K4: exclusive scan of counts -> offsets[0..N], single block, wave-level scan
// ---------------------------------------------------------------------------
__global__ __launch_bounds__(1024) void scan_kernel(const int* __restrict__ counts,
                                                    int* __restrict__ offsets) {
    __shared__ int wsum[16];
    __shared__ int s_run;
    const int t = threadIdx.x;
    const int lane = t & 63, wv = t >> 6;
    if (t == 0) s_run = 0;
    __syncthreads();
    for (int base = 0; base < N_NODES; base += 1024) {
        const int i = base + t;
        const int v = (i < N_NODES) ? counts[i] : 0;
        int x = v;
        #pragma unroll
        for (int off = 1; off < 64; off <<= 1) {
            const int y = __shfl_up(x, off);
            if (lane >= off) x += y;
        }
        if (lane == 63) wsum[wv] = x;
        __syncthreads();
        int wbase = 0, ctot = 0;
        #pragma unroll
        for (int w = 0; w < 16; w++) {
            const int val = wsum[w];
            ctot += val;
            if (w < wv) wbase += val;
        }
        const int run = s_run;
        if (i < N_NODES) offsets[i] = run + wbase + (x - v);  // exclusive
        __syncthreads();
        if (t == 0) s_run = run + ctot;
        __syncthreads();
    }
    if (t == 0) offsets[N_NODES] = s_run;
}

// ---------------------------------------------------------------------------
// K5: scatter edge sources into CSR order (cursor = counts array, re-zeroed)
// ---------------------------------------------------------------------------
__global__ void scatter_kernel(const int* __restrict__ ei,
                               const int* __restrict__ offsets,
                               int* __restrict__ cursor,
                               int* __restrict__ esrc) {
    const int e = blockIdx.x * 256 + threadIdx.x;
    if (e >= ET) return;
    int s, d;
    if (e < E_EDGES) { s = ei[e]; d = ei[E_EDGES + e]; }
    else             { s = e - E_EDGES; d = s; }
    const int pos = offsets[d] + atomicAdd(&cursor[d], 1);
    esrc[pos] = s;
}

// ---------------------------------------------------------------------------
// K6: per-destination online-softmax + weighted aggregation. One wave / node,
// each lane owns 2 of the 128 output features.
// ---------------------------------------------------------------------------
__global__ __launch_bounds__(256) void aggregate_kernel(
    const float* __restrict__ h, const int* __restrict__ offsets,
    const int* __restrict__ esrc, const float* __restrict__ s_dst,
    const float* __restrict__ s_src, const float* __restrict__ bias,
    float* __restrict__ out) {
    const int node = (blockIdx.x * 256 + threadIdx.x) >> 6;
    const int lane = threadIdx.x & 63;
    if (node >= N_NODES) return;
    const int beg = offsets[node], end = offsets[node + 1];
    const float sd = s_dst[node];
    float m = -1e30f, denom = 0.f;
    float2 acc = make_float2(0.f, 0.f);
    for (int e = beg; e < end; e++) {
        const int s = esrc[e];
        float a = sd + s_src[s];
        a = (a > 0.f) ? a : NEG_SLOPE * a;
        if (a > m) {                      // wave-uniform branch
            const float r = __expf(m - a);
            denom *= r;
            acc.x *= r; acc.y *= r;
            m = a;
        }
        const float w = __expf(a - m);
        denom += w;
        const float2 hv = *(const float2*)(h + (size_t)s * C_OUT + lane * 2);
        acc.x += w * hv.x;
        acc.y += w * hv.y;
    }
    const float inv = 1.f / (denom + 1e-16f);
    const float2 bv = *(const float2*)(bias + lane * 2);
    float2 o = make_float2(acc.x * inv + bv.x, acc.y * inv + bv.y);
    *(float2*)(out + (size_t)node * C_OUT + lane * 2) = o;
}

// ---------------------------------------------------------------------------
extern "C" void kernel_launch(void* const* d_in, const int* in_sizes, int n_in,
                              void* d_out, int out_size, void* d_ws, size_t ws_size,
                              hipStream_t stream) {
    const float* x    = (const float*)d_in[0];
    const int*   ei   = (const int*)d_in[1];
    const float* W    = (const float*)d_in[2];
    const float* att  = (const float*)d_in[3];
    const float* bias = (const float*)d_in[4];
    float* out = (float*)d_out;

    // workspace layout (~30 MB)
    float* h       = (float*)d_ws;
    float* s_src   = h + (size_t)N_NODES * C_OUT;
    float* s_dst   = s_src + N_NODES;
    int*   counts  = (int*)(s_dst + N_NODES);
    int*   offsets = counts + N_NODES;
    int*   esrc    = offsets + N_NODES + 1;

    hipMemsetAsync(counts, 0, N_NODES * sizeof(int), stream);

    gemm_kernel<<<(N_NODES + 63) / 64, 256, 0, stream>>>(x, W, h);
    snode_kernel<<<(N_NODES * 64 + 255) / 256, 256, 0, stream>>>(h, att, s_dst, s_src);
    count_kernel<<<(ET + 255) / 256, 256, 0, stream>>>(ei, counts);
    scan_kernel<<<1, 1024, 0, stream>>>(counts, offsets);
    hipMemsetAsync(counts, 0, N_NODES * sizeof(int), stream);
    scatter_kernel<<<(ET + 255) / 256, 256, 0, stream>>>(ei, offsets, counts, esrc);
    aggregate_kernel<<<(N_NODES * 64 + 255) / 256, 256, 0, stream>>>(
        h, offsets, esrc, s_dst, s_src, bias, out);
}

// Round 2
// 209.414 us; speedup vs baseline: 1.4959x; 1.4959x over previous
//
#include <hip/hip_runtime.h>
#include <hip/hip_bf16.h>

constexpr int N_NODES = 50000;
constexpr int DIN     = 256;
constexpr int C_OUT   = 128;
constexpr int E_EDGES = 800000;
constexpr int ET      = E_EDGES + N_NODES;   // with self-loops
constexpr float NEG_SLOPE = 0.2f;
constexpr int NSCB = (N_NODES + 1023) / 1024;  // 49 scan blocks

typedef __attribute__((ext_vector_type(8))) short short8v;
typedef __attribute__((ext_vector_type(4))) float f32x4;

static __device__ __forceinline__ short f2bf(float f) {
    __hip_bfloat16 b = __float2bfloat16(f);
    return *reinterpret_cast<short*>(&b);
}

// ---------------------------------------------------------------------------
// K0: Wt[col][k] = bf16(W[k][col])   (128 x 256 bf16, 64 KB, L2-resident)
// ---------------------------------------------------------------------------
__global__ void wconv_kernel(const float* __restrict__ W, ushort* __restrict__ wt) {
    const int idx = blockIdx.x * 256 + threadIdx.x;
    if (idx >= DIN * C_OUT) return;
    const int k = idx >> 7, col = idx & 127;
    __hip_bfloat16 b = __float2bfloat16(W[idx]);
    wt[col * DIN + k] = *reinterpret_cast<ushort*>(&b);
}

// ---------------------------------------------------------------------------
// K1: h = x @ W via bf16 MFMA (16x16x32), no LDS.
//     Wave = 16 rows x 128 cols. A-frags per-lane from x (fp32->bf16 in regs),
//     B-frags from Wt (global, L2). Epilogue fuses s_dst/s_src = h . att.
// ---------------------------------------------------------------------------
__global__ __launch_bounds__(256) void gemm_mfma(const float* __restrict__ x,
                                                 const ushort* __restrict__ wt,
                                                 const float* __restrict__ att,
                                                 float* __restrict__ h,
                                                 float* __restrict__ s_dst,
                                                 float* __restrict__ s_src) {
    const int lane  = threadIdx.x & 63;
    const int wv    = threadIdx.x >> 6;
    const int rowbase = (blockIdx.x * 4 + wv) * 16;
    const int col16 = lane & 15;
    const int kgrp  = lane >> 4;        // 0..3

    int arow = rowbase + col16;         // A row owned by this lane
    if (arow >= N_NODES) arow = N_NODES - 1;   // clamp (dup compute, guarded store)
    const float* xr = x + (size_t)arow * DIN + kgrp * 8;

    f32x4 acc[8] = {};
    #pragma unroll
    for (int ks = 0; ks < 8; ks++) {
        const int k0 = ks * 32;
        const float4 v0 = *(const float4*)(xr + k0);
        const float4 v1 = *(const float4*)(xr + k0 + 4);
        short8v a;
        a[0] = f2bf(v0.x); a[1] = f2bf(v0.y); a[2] = f2bf(v0.z); a[3] = f2bf(v0.w);
        a[4] = f2bf(v1.x); a[5] = f2bf(v1.y); a[6] = f2bf(v1.z); a[7] = f2bf(v1.w);
        #pragma unroll
        for (int c = 0; c < 8; c++) {
            const short8v b = *(const short8v*)(wt + (size_t)(c * 16 + col16) * DIN + k0 + kgrp * 8);
            acc[c] = __builtin_amdgcn_mfma_f32_16x16x32_bf16(a, b, acc[c], 0, 0, 0);
        }
    }

    // epilogue: store h (fp32) + fused attention dot products
    float attd[8], atts[8];
    #pragma unroll
    for (int c = 0; c < 8; c++) {
        attd[c] = att[c * 16 + col16];
        atts[c] = att[C_OUT + c * 16 + col16];
    }
    float pd[4] = {}, ps[4] = {};
    #pragma unroll
    for (int j = 0; j < 4; j++) {
        const int row = rowbase + kgrp * 4 + j;   // C/D: col=lane&15, row=(lane>>4)*4+j
        const bool ok = (row < N_NODES);
        #pragma unroll
        for (int c = 0; c < 8; c++) {
            const float hv = acc[c][j];
            pd[j] += hv * attd[c];
            ps[j] += hv * atts[c];
            if (ok) h[(size_t)row * C_OUT + c * 16 + col16] = hv;
        }
    }
    #pragma unroll
    for (int j = 0; j < 4; j++) {
        float d = pd[j], s = ps[j];
        #pragma unroll
        for (int off = 1; off < 16; off <<= 1) {   // reduce within 16-lane group
            d += __shfl_xor(d, off);
            s += __shfl_xor(s, off);
        }
        const int row = rowbase + kgrp * 4 + j;
        if (col16 == 0 && row < N_NODES) { s_dst[row] = d; s_src[row] = s; }
    }
}

// ---------------------------------------------------------------------------
// K2: count edges per destination (self-loops implicit for e >= E)
// ---------------------------------------------------------------------------
__global__ void count_kernel(const int* __restrict__ ei, int* __restrict__ counts) {
    const int e = blockIdx.x * 256 + threadIdx.x;
    if (e >= ET) return;
    const int d = (e < E_EDGES) ? ei[E_EDGES + e] : (e - E_EDGES);
    atomicAdd(&counts[d], 1);
}

// ---------------------------------------------------------------------------
// K3a/b/c: hierarchical exclusive scan of counts -> offsets[0..N]
// ---------------------------------------------------------------------------
__global__ __launch_bounds__(256) void scan_bsum(const int* __restrict__ counts,
                                                 int* __restrict__ bsum) {
    const int t = threadIdx.x;
    const int i0 = blockIdx.x * 1024 + t * 4;
    int s = 0;
    #pragma unroll
    for (int j = 0; j < 4; j++) { const int i = i0 + j; if (i < N_NODES) s += counts[i]; }
    #pragma unroll
    for (int off = 32; off; off >>= 1) s += __shfl_xor(s, off);
    __shared__ int wsum[4];
    if ((t & 63) == 0) wsum[t >> 6] = s;
    __syncthreads();
    if (t == 0) bsum[blockIdx.x] = wsum[0] + wsum[1] + wsum[2] + wsum[3];
}

__global__ void scan_bbase(const int* __restrict__ bsum, int* __restrict__ bbase,
                           int* __restrict__ offsets) {
    const int lane = threadIdx.x;   // 64 threads
    const int v = (lane < NSCB) ? bsum[lane] : 0;
    int x = v;
    #pragma unroll
    for (int off = 1; off < 64; off <<= 1) {
        const int y = __shfl_up(x, off);
        if (lane >= off) x += y;
    }
    if (lane < NSCB) bbase[lane] = x - v;      // exclusive
    if (lane == 63) offsets[N_NODES] = x;      // grand total (== ET)
}

__global__ __launch_bounds__(256) void scan_final(const int* __restrict__ counts,
                                                  const int* __restrict__ bbase,
                                                  int* __restrict__ offsets) {
    const int t = threadIdx.x;
    const int i0 = blockIdx.x * 1024 + t * 4;
    const int lane = t & 63, wv = t >> 6;
    int c[4];
    #pragma unroll
    for (int j = 0; j < 4; j++) { const int i = i0 + j; c[j] = (i < N_NODES) ? counts[i] : 0; }
    const int tsum = c[0] + c[1] + c[2] + c[3];
    int x = tsum;
    #pragma unroll
    for (int off = 1; off < 64; off <<= 1) {
        const int y = __shfl_up(x, off);
        if (lane >= off) x += y;
    }
    __shared__ int wsum[4];
    if (lane == 63) wsum[wv] = x;
    __syncthreads();
    int wbase = 0;
    #pragma unroll
    for (int w = 0; w < 4; w++) if (w < wv) wbase += wsum[w];
    int base = bbase[blockIdx.x] + wbase + (x - tsum);
    #pragma unroll
    for (int j = 0; j < 4; j++) {
        const int i = i0 + j;
        if (i < N_NODES) offsets[i] = base;
        base += c[j];
    }
}

// ---------------------------------------------------------------------------
// K4: scatter edge sources into CSR order (cursor = counts array, re-zeroed)
// ---------------------------------------------------------------------------
__global__ void scatter_kernel(const int* __restrict__ ei,
                               const int* __restrict__ offsets,
                               int* __restrict__ cursor,
                               int* __restrict__ esrc) {
    const int e = blockIdx.x * 256 + threadIdx.x;
    if (e >= ET) return;
    int s, d;
    if (e < E_EDGES) { s = ei[e]; d = ei[E_EDGES + e]; }
    else             { s = e - E_EDGES; d = s; }
    const int pos = offsets[d] + atomicAdd(&cursor[d], 1);
    esrc[pos] = s;
}

// ---------------------------------------------------------------------------
// K5: aggregation. One wave/node. Phase 1: wave-parallel softmax max+denom
//     (scalar gathers only). Phase 2: precomputed weights -> independent
//     h-row gathers, unrolled x4 for ILP.
// ---------------------------------------------------------------------------
__global__ __launch_bounds__(256) void aggregate_kernel(
    const float* __restrict__ h, const int* __restrict__ offsets,
    const int* __restrict__ esrc, const float* __restrict__ s_dst,
    const float* __restrict__ s_src, const float* __restrict__ bias,
    float* __restrict__ out) {
    const int node = (blockIdx.x * 256 + threadIdx.x) >> 6;
    const int lane = threadIdx.x & 63;
    if (node >= N_NODES) return;
    const int beg = offsets[node], end = offsets[node + 1];
    const float sd = s_dst[node];

    // phase 1: m and denom, one edge per lane
    float m = -1e30f, den = 0.f;
    for (int b = beg; b < end; b += 64) {
        const int e = b + lane;
        float a = -1e30f;
        if (e < end) {
            const int s = esrc[e];
            const float t = sd + s_src[s];
            a = (t > 0.f) ? t : NEG_SLOPE * t;
        }
        float cm = a;
        #pragma unroll
        for (int off = 32; off; off >>= 1) cm = fmaxf(cm, __shfl_xor(cm, off));
        float w = (e < end) ? __expf(a - cm) : 0.f;
        float cd = w;
        #pragma unroll
        for (int off = 32; off; off >>= 1) cd += __shfl_xor(cd, off);
        const float mn = fmaxf(m, cm);
        den = den * __expf(m - mn) + cd * __expf(cm - mn);
        m = mn;
    }
    const float inv = 1.f / (den + 1e-16f);

    // phase 2: weighted aggregation, independent gathers
    float accx = 0.f, accy = 0.f;
    const float2* __restrict__ hb = (const float2*)h;
    for (int b = beg; b < end; b += 64) {
        const int e = b + lane;
        const int cnt = min(64, end - b);
        int s = 0; float w = 0.f;
        if (e < end) {
            s = esrc[e];
            float t = sd + s_src[s];
            t = (t > 0.f) ? t : NEG_SLOPE * t;
            w = __expf(t - m) * inv;
        }
        int j = 0;
        for (; j + 4 <= cnt; j += 4) {
            const float w0 = __shfl(w, j),     w1 = __shfl(w, j + 1);
            const float w2 = __shfl(w, j + 2), w3 = __shfl(w, j + 3);
            const int   s0 = __shfl(s, j),     s1 = __shfl(s, j + 1);
            const int   s2 = __shfl(s, j + 2), s3 = __shfl(s, j + 3);
            const float2 h0 = hb[(size_t)s0 * 64 + lane];
            const float2 h1 = hb[(size_t)s1 * 64 + lane];
            const float2 hh2 = hb[(size_t)s2 * 64 + lane];
            const float2 h3 = hb[(size_t)s3 * 64 + lane];
            accx += w0 * h0.x + w1 * h1.x + w2 * hh2.x + w3 * h3.x;
            accy += w0 * h0.y + w1 * h1.y + w2 * hh2.y + w3 * h3.y;
        }
        for (; j < cnt; j++) {
            const float wj = __shfl(w, j);
            const int   sj = __shfl(s, j);
            const float2 hv = hb[(size_t)sj * 64 + lane];
            accx += wj * hv.x;
            accy += wj * hv.y;
        }
    }
    const float2 bv = ((const float2*)bias)[lane];
    float2 o = make_float2(accx + bv.x, accy + bv.y);
    ((float2*)out)[(size_t)node * 64 + lane] = o;
}

// ---------------------------------------------------------------------------
extern "C" void kernel_launch(void* const* d_in, const int* in_sizes, int n_in,
                              void* d_out, int out_size, void* d_ws, size_t ws_size,
                              hipStream_t stream) {
    const float* x    = (const float*)d_in[0];
    const int*   ei   = (const int*)d_in[1];
    const float* W    = (const float*)d_in[2];
    const float* att  = (const float*)d_in[3];
    const float* bias = (const float*)d_in[4];
    float* out = (float*)d_out;

    // workspace layout (~30 MB); wt first for 16 B alignment of short8v loads
    ushort* wt     = (ushort*)d_ws;                       // 128*256
    float*  h      = (float*)(wt + DIN * C_OUT);          // N*128
    float*  s_src  = h + (size_t)N_NODES * C_OUT;
    float*  s_dst  = s_src + N_NODES;
    int*    counts = (int*)(s_dst + N_NODES);
    int*    offsets = counts + N_NODES;                   // N+1
    int*    esrc   = offsets + N_NODES + 1;               // ET
    int*    bsum   = esrc + ET;                           // NSCB
    int*    bbase  = bsum + 64;                           // NSCB

    hipMemsetAsync(counts, 0, N_NODES * sizeof(int), stream);

    wconv_kernel<<<(DIN * C_OUT + 255) / 256, 256, 0, stream>>>(W, wt);
    gemm_mfma<<<(N_NODES + 63) / 64, 256, 0, stream>>>(x, wt, att, h, s_dst, s_src);
    count_kernel<<<(ET + 255) / 256, 256, 0, stream>>>(ei, counts);
    scan_bsum<<<NSCB, 256, 0, stream>>>(counts, bsum);
    scan_bbase<<<1, 64, 0, stream>>>(bsum, bbase, offsets);
    scan_final<<<NSCB, 256, 0, stream>>>(counts, bbase, offsets);
    hipMemsetAsync(counts, 0, N_NODES * sizeof(int), stream);
    scatter_kernel<<<(ET + 255) / 256, 256, 0, stream>>>(ei, offsets, counts, esrc);
    aggregate_kernel<<<(N_NODES * 64 + 255) / 256, 256, 0, stream>>>(
        h, offsets, esrc, s_dst, s_src, bias, out);
}

// Round 3
// 168.673 us; speedup vs baseline: 1.8572x; 1.2415x over previous
//
#include <hip/hip_runtime.h>
#include <hip/hip_bf16.h>

constexpr int N_NODES = 50000;
constexpr int DIN     = 256;
constexpr int C_OUT   = 128;
constexpr int E_EDGES = 800000;
constexpr int ET      = E_EDGES + N_NODES;   // with self-loops
constexpr float NEG_SLOPE = 0.2f;
constexpr int NSCB = (N_NODES + 1023) / 1024;  // 49 scan blocks

typedef __attribute__((ext_vector_type(8))) short short8v;
typedef __attribute__((ext_vector_type(4))) float f32x4;

static __device__ __forceinline__ ushort f2bf(float f) {
    __hip_bfloat16 b = __float2bfloat16(f);
    return *reinterpret_cast<ushort*>(&b);
}

// ---------------------------------------------------------------------------
// K0: Wt[col][k] = bf16(W[k][col])  + zero the counts array (fused)
// ---------------------------------------------------------------------------
__global__ void wconv_kernel(const float* __restrict__ W, ushort* __restrict__ wt,
                             int* __restrict__ counts) {
    const int idx = blockIdx.x * 256 + threadIdx.x;
    if (idx < DIN * C_OUT) {
        const int k = idx >> 7, col = idx & 127;
        wt[col * DIN + k] = f2bf(W[idx]);
    }
    if (idx < N_NODES) counts[idx] = 0;
}

// ---------------------------------------------------------------------------
// K1: h = x @ W via bf16 MFMA (16x16x32), no LDS. h stored in BF16.
//     Epilogue fuses s_dst/s_src = h . att (computed from fp32 acc).
// ---------------------------------------------------------------------------
__global__ __launch_bounds__(256) void gemm_mfma(const float* __restrict__ x,
                                                 const ushort* __restrict__ wt,
                                                 const float* __restrict__ att,
                                                 ushort* __restrict__ hb,
                                                 float* __restrict__ s_dst,
                                                 float* __restrict__ s_src) {
    const int lane  = threadIdx.x & 63;
    const int wv    = threadIdx.x >> 6;
    const int rowbase = (blockIdx.x * 4 + wv) * 16;
    const int col16 = lane & 15;
    const int kgrp  = lane >> 4;        // 0..3

    int arow = rowbase + col16;         // A row owned by this lane
    if (arow >= N_NODES) arow = N_NODES - 1;   // clamp (dup compute, guarded store)
    const float* xr = x + (size_t)arow * DIN + kgrp * 8;

    f32x4 acc[8] = {};
    #pragma unroll
    for (int ks = 0; ks < 8; ks++) {
        const int k0 = ks * 32;
        const float4 v0 = *(const float4*)(xr + k0);
        const float4 v1 = *(const float4*)(xr + k0 + 4);
        short8v a;
        a[0] = f2bf(v0.x); a[1] = f2bf(v0.y); a[2] = f2bf(v0.z); a[3] = f2bf(v0.w);
        a[4] = f2bf(v1.x); a[5] = f2bf(v1.y); a[6] = f2bf(v1.z); a[7] = f2bf(v1.w);
        #pragma unroll
        for (int c = 0; c < 8; c++) {
            const short8v b = *(const short8v*)(wt + (size_t)(c * 16 + col16) * DIN + k0 + kgrp * 8);
            acc[c] = __builtin_amdgcn_mfma_f32_16x16x32_bf16(a, b, acc[c], 0, 0, 0);
        }
    }

    // epilogue: store h (bf16) + fused attention dot products
    float attd[8], atts[8];
    #pragma unroll
    for (int c = 0; c < 8; c++) {
        attd[c] = att[c * 16 + col16];
        atts[c] = att[C_OUT + c * 16 + col16];
    }
    float pd[4] = {}, ps[4] = {};
    #pragma unroll
    for (int j = 0; j < 4; j++) {
        const int row = rowbase + kgrp * 4 + j;   // C/D: col=lane&15, row=(lane>>4)*4+j
        const bool ok = (row < N_NODES);
        #pragma unroll
        for (int c = 0; c < 8; c++) {
            const float hv = acc[c][j];
            pd[j] += hv * attd[c];
            ps[j] += hv * atts[c];
            if (ok) hb[(size_t)row * C_OUT + c * 16 + col16] = f2bf(hv);
        }
    }
    #pragma unroll
    for (int j = 0; j < 4; j++) {
        float d = pd[j], s = ps[j];
        #pragma unroll
        for (int off = 1; off < 16; off <<= 1) {   // reduce within 16-lane group
            d += __shfl_xor(d, off);
            s += __shfl_xor(s, off);
        }
        const int row = rowbase + kgrp * 4 + j;
        if (col16 == 0 && row < N_NODES) { s_dst[row] = d; s_src[row] = s; }
    }
}

// ---------------------------------------------------------------------------
// K2: count edges per destination (self-loops implicit for e >= E)
// ---------------------------------------------------------------------------
__global__ void count_kernel(const int* __restrict__ ei, int* __restrict__ counts) {
    const int e = blockIdx.x * 256 + threadIdx.x;
    if (e >= ET) return;
    const int d = (e < E_EDGES) ? ei[E_EDGES + e] : (e - E_EDGES);
    atomicAdd(&counts[d], 1);
}

// ---------------------------------------------------------------------------
// K3a/b/c: hierarchical exclusive scan of counts -> offsets[0..N]
// ---------------------------------------------------------------------------
__global__ __launch_bounds__(256) void scan_bsum(const int* __restrict__ counts,
                                                 int* __restrict__ bsum) {
    const int t = threadIdx.x;
    const int i0 = blockIdx.x * 1024 + t * 4;
    int s = 0;
    #pragma unroll
    for (int j = 0; j < 4; j++) { const int i = i0 + j; if (i < N_NODES) s += counts[i]; }
    #pragma unroll
    for (int off = 32; off; off >>= 1) s += __shfl_xor(s, off);
    __shared__ int wsum[4];
    if ((t & 63) == 0) wsum[t >> 6] = s;
    __syncthreads();
    if (t == 0) bsum[blockIdx.x] = wsum[0] + wsum[1] + wsum[2] + wsum[3];
}

__global__ void scan_bbase(const int* __restrict__ bsum, int* __restrict__ bbase,
                           int* __restrict__ offsets) {
    const int lane = threadIdx.x;   // 64 threads
    const int v = (lane < NSCB) ? bsum[lane] : 0;
    int x = v;
    #pragma unroll
    for (int off = 1; off < 64; off <<= 1) {
        const int y = __shfl_up(x, off);
        if (lane >= off) x += y;
    }
    if (lane < NSCB) bbase[lane] = x - v;      // exclusive
    if (lane == 63) offsets[N_NODES] = x;      // grand total (== ET)
}

__global__ __launch_bounds__(256) void scan_final(const int* __restrict__ counts_in,
                                                  const int* __restrict__ bbase,
                                                  int* __restrict__ offsets,
                                                  int* __restrict__ counts_clr) {
    const int t = threadIdx.x;
    const int i0 = blockIdx.x * 1024 + t * 4;
    const int lane = t & 63, wv = t >> 6;
    int c[4];
    #pragma unroll
    for (int j = 0; j < 4; j++) { const int i = i0 + j; c[j] = (i < N_NODES) ? counts_in[i] : 0; }
    const int tsum = c[0] + c[1] + c[2] + c[3];
    int x = tsum;
    #pragma unroll
    for (int off = 1; off < 64; off <<= 1) {
        const int y = __shfl_up(x, off);
        if (lane >= off) x += y;
    }
    __shared__ int wsum[4];
    if (lane == 63) wsum[wv] = x;
    __syncthreads();
    int wbase = 0;
    #pragma unroll
    for (int w = 0; w < 4; w++) if (w < wv) wbase += wsum[w];
    int base = bbase[blockIdx.x] + wbase + (x - tsum);
    #pragma unroll
    for (int j = 0; j < 4; j++) {
        const int i = i0 + j;
        if (i < N_NODES) { offsets[i] = base; counts_clr[i] = 0; }  // re-zero for cursor
        base += c[j];
    }
}

// ---------------------------------------------------------------------------
// K4: scatter edge sources into CSR order (cursor = counts array, re-zeroed)
// ---------------------------------------------------------------------------
__global__ void scatter_kernel(const int* __restrict__ ei,
                               const int* __restrict__ offsets,
                               int* __restrict__ cursor,
                               int* __restrict__ esrc) {
    const int e = blockIdx.x * 256 + threadIdx.x;
    if (e >= ET) return;
    int s, d;
    if (e < E_EDGES) { s = ei[e]; d = ei[E_EDGES + e]; }
    else             { s = e - E_EDGES; d = s; }
    const int pos = offsets[d] + atomicAdd(&cursor[d], 1);
    esrc[pos] = s;
}

// ---------------------------------------------------------------------------
// K5: aggregation, single pass. exp without max-subtraction (|alpha| <~ 13,
// safe in fp32; ratios identical). bf16 h gathers (256 B/row). One wave/node.
// ---------------------------------------------------------------------------
__global__ __launch_bounds__(256) void aggregate_kernel(
    const ushort* __restrict__ hb, const int* __restrict__ offsets,
    const int* __restrict__ esrc, const float* __restrict__ s_dst,
    const float* __restrict__ s_src, const float* __restrict__ bias,
    float* __restrict__ out) {
    const int node = (blockIdx.x * 256 + threadIdx.x) >> 6;
    const int lane = threadIdx.x & 63;
    if (node >= N_NODES) return;
    const int beg = offsets[node], end = offsets[node + 1];
    const float sd = s_dst[node];
    const uint* __restrict__ hu = (const uint*)hb;

    float den = 0.f, accx = 0.f, accy = 0.f;
    for (int b = beg; b < end; b += 64) {
        const int e = b + lane;
        const int cnt = min(64, end - b);
        int s = 0; float w = 0.f;
        if (e < end) {
            s = esrc[e];
            float t = sd + s_src[s];
            t = (t > 0.f) ? t : NEG_SLOPE * t;
            w = __expf(t);
            den += w;
        }
        int j = 0;
        for (; j + 4 <= cnt; j += 4) {
            const int   s0 = __shfl(s, j),     s1 = __shfl(s, j + 1);
            const int   s2 = __shfl(s, j + 2), s3 = __shfl(s, j + 3);
            const float w0 = __shfl(w, j),     w1 = __shfl(w, j + 1);
            const float w2 = __shfl(w, j + 2), w3 = __shfl(w, j + 3);
            const uint v0 = hu[(size_t)s0 * 64 + lane];
            const uint v1 = hu[(size_t)s1 * 64 + lane];
            const uint v2 = hu[(size_t)s2 * 64 + lane];
            const uint v3 = hu[(size_t)s3 * 64 + lane];
            accx += w0 * __uint_as_float(v0 << 16) + w1 * __uint_as_float(v1 << 16)
                  + w2 * __uint_as_float(v2 << 16) + w3 * __uint_as_float(v3 << 16);
            accy += w0 * __uint_as_float(v0 & 0xffff0000u) + w1 * __uint_as_float(v1 & 0xffff0000u)
                  + w2 * __uint_as_float(v2 & 0xffff0000u) + w3 * __uint_as_float(v3 & 0xffff0000u);
        }
        for (; j < cnt; j++) {
            const int   sj = __shfl(s, j);
            const float wj = __shfl(w, j);
            const uint  v  = hu[(size_t)sj * 64 + lane];
            accx += wj * __uint_as_float(v << 16);
            accy += wj * __uint_as_float(v & 0xffff0000u);
        }
    }
    #pragma unroll
    for (int off = 32; off; off >>= 1) den += __shfl_xor(den, off);
    const float inv = 1.f / (den + 1e-16f);
    const float2 bv = ((const float2*)bias)[lane];
    ((float2*)out)[(size_t)node * 64 + lane] =
        make_float2(accx * inv + bv.x, accy * inv + bv.y);
}

// ---------------------------------------------------------------------------
extern "C" void kernel_launch(void* const* d_in, const int* in_sizes, int n_in,
                              void* d_out, int out_size, void* d_ws, size_t ws_size,
                              hipStream_t stream) {
    const float* x    = (const float*)d_in[0];
    const int*   ei   = (const int*)d_in[1];
    const float* W    = (const float*)d_in[2];
    const float* att  = (const float*)d_in[3];
    const float* bias = (const float*)d_in[4];
    float* out = (float*)d_out;

    // workspace layout (~18 MB); wt first for 16 B alignment of short8v loads
    ushort* wt     = (ushort*)d_ws;                       // 128*256
    ushort* hbuf   = wt + DIN * C_OUT;                    // N*128 bf16
    float*  s_src  = (float*)(hbuf + (size_t)N_NODES * C_OUT);
    float*  s_dst  = s_src + N_NODES;
    int*    counts = (int*)(s_dst + N_NODES);
    int*    offsets = counts + N_NODES;                   // N+1
    int*    esrc   = offsets + N_NODES + 1;               // ET
    int*    bsum   = esrc + ET;                           // NSCB
    int*    bbase  = bsum + 64;                           // NSCB

    wconv_kernel<<<(N_NODES + 255) / 256, 256, 0, stream>>>(W, wt, counts);
    gemm_mfma<<<(N_NODES + 63) / 64, 256, 0, stream>>>(x, wt, att, hbuf, s_dst, s_src);
    count_kernel<<<(ET + 255) / 256, 256, 0, stream>>>(ei, counts);
    scan_bsum<<<NSCB, 256, 0, stream>>>(counts, bsum);
    scan_bbase<<<1, 64, 0, stream>>>(bsum, bbase, offsets);
    scan_final<<<NSCB, 256, 0, stream>>>(counts, bbase, offsets, counts);
    scatter_kernel<<<(ET + 255) / 256, 256, 0, stream>>>(ei, offsets, counts, esrc);
    aggregate_kernel<<<(N_NODES * 64 + 255) / 256, 256, 0, stream>>>(
        hbuf, offsets, esrc, s_dst, s_src, bias, out);
}

// Round 4
// 107.458 us; speedup vs baseline: 2.9152x; 1.5697x over previous
//
#include <hip/hip_runtime.h>
#include <hip/hip_bf16.h>

constexpr int N_NODES = 50000;
constexpr int DIN     = 256;
constexpr int C_OUT   = 128;
constexpr int E_EDGES = 800000;
constexpr int ET      = E_EDGES + N_NODES;   // with self-loops
constexpr float NEG_SLOPE = 0.2f;

constexpr int GEMM_RPB    = 128;  // rows per block (4 waves x 32)
constexpr int GEMM_BLOCKS = (N_NODES + GEMM_RPB - 1) / GEMM_RPB;        // 391
constexpr int LINK_EPB    = 2048; // edges per link block (256 thr x 8)
constexpr int LINK_BLOCKS = (ET + LINK_EPB - 1) / LINK_EPB;             // 416

typedef __attribute__((ext_vector_type(8))) short short8v;
typedef __attribute__((ext_vector_type(4))) float f32x4;

static __device__ __forceinline__ ushort f2bf(float f) {
    __hip_bfloat16 b = __float2bfloat16(f);
    return *reinterpret_cast<ushort*>(&b);
}
static __device__ __forceinline__ short f2bfs(float f) {
    __hip_bfloat16 b = __float2bfloat16(f);
    return *reinterpret_cast<short*>(&b);
}

// ---------------------------------------------------------------------------
// K0: Wt -> bf16, fragment-ordered for linear ds_read_b128; + head[] = -1.
// fragpos(ks,c,kgrp,col16,j) = ((ks*8+c)*64 + kgrp*16 + col16)*8 + j
//   where element is W[k][col], k = ks*32+kgrp*8+j, col = c*16+col16.
// ---------------------------------------------------------------------------
__global__ void wconv_kernel(const float* __restrict__ W, ushort* __restrict__ wt,
                             int* __restrict__ head) {
    const int idx = blockIdx.x * 256 + threadIdx.x;
    if (idx < DIN * C_OUT) {
        const int k = idx >> 7, col = idx & 127;
        const int ks = k >> 5, kgrp = (k >> 3) & 3, j = k & 7;
        const int c = col >> 4, col16 = col & 15;
        const int fragpos = ((ks * 8 + c) * 64 + kgrp * 16 + col16) * 8 + j;
        wt[fragpos] = f2bf(W[idx]);
    }
    if (idx < N_NODES) head[idx] = -1;
}

// ---------------------------------------------------------------------------
// K1 (fused): blocks [0,GEMM_BLOCKS): h = x@W via MFMA with LDS-staged Wt;
//             blocks [GEMM_BLOCKS, +LINK_BLOCKS): linked-list build
//             next[e] = atomicExch(&head[dst], e)   (independent work).
// ---------------------------------------------------------------------------
__global__ __launch_bounds__(256) void gemm_link(const float* __restrict__ x,
                                                 const ushort* __restrict__ wt,
                                                 const float* __restrict__ att,
                                                 const int* __restrict__ ei,
                                                 ushort* __restrict__ hb,
                                                 float* __restrict__ s_dst,
                                                 float* __restrict__ s_src,
                                                 int* __restrict__ head,
                                                 int* __restrict__ nxt) {
    __shared__ ushort lw[DIN * C_OUT];   // 64 KB, fragment-ordered
    const int t = threadIdx.x;

    if (blockIdx.x >= GEMM_BLOCKS) {     // ---- linked-list build path ----
        const int b = blockIdx.x - GEMM_BLOCKS;
        #pragma unroll
        for (int i = 0; i < 8; i++) {
            const int e = b * LINK_EPB + i * 256 + t;
            if (e < ET) {
                const int d = (e < E_EDGES) ? ei[E_EDGES + e] : (e - E_EDGES);
                nxt[e] = atomicExch(&head[d], e);
            }
        }
        return;
    }

    // ---- GEMM path ----
    {   // stage Wt (64 KB contiguous) into LDS
        const uint4* src = (const uint4*)wt;
        uint4* dst = (uint4*)lw;
        #pragma unroll
        for (int i = 0; i < 16; i++) dst[t + i * 256] = src[t + i * 256];
    }
    __syncthreads();

    const int lane = t & 63, wv = t >> 6;
    const int col16 = lane & 15, kgrp = lane >> 4;
    const int rowbase = blockIdx.x * GEMM_RPB + wv * 32;
    int r0 = rowbase + col16;      if (r0 >= N_NODES) r0 = N_NODES - 1;
    int r1 = rowbase + 16 + col16; if (r1 >= N_NODES) r1 = N_NODES - 1;
    const float* xr0 = x + (size_t)r0 * DIN + kgrp * 8;
    const float* xr1 = x + (size_t)r1 * DIN + kgrp * 8;

    f32x4 acc[2][8] = {};
    const short8v* lwf = (const short8v*)lw;
    #pragma unroll
    for (int ks = 0; ks < 8; ks++) {
        const float4 v0 = *(const float4*)(xr0 + ks * 32);
        const float4 v1 = *(const float4*)(xr0 + ks * 32 + 4);
        const float4 u0 = *(const float4*)(xr1 + ks * 32);
        const float4 u1 = *(const float4*)(xr1 + ks * 32 + 4);
        short8v a0, a1;
        a0[0] = f2bfs(v0.x); a0[1] = f2bfs(v0.y); a0[2] = f2bfs(v0.z); a0[3] = f2bfs(v0.w);
        a0[4] = f2bfs(v1.x); a0[5] = f2bfs(v1.y); a0[6] = f2bfs(v1.z); a0[7] = f2bfs(v1.w);
        a1[0] = f2bfs(u0.x); a1[1] = f2bfs(u0.y); a1[2] = f2bfs(u0.z); a1[3] = f2bfs(u0.w);
        a1[4] = f2bfs(u1.x); a1[5] = f2bfs(u1.y); a1[6] = f2bfs(u1.z); a1[7] = f2bfs(u1.w);
        #pragma unroll
        for (int c = 0; c < 8; c++) {
            const short8v bfr = lwf[(ks * 8 + c) * 64 + lane];
            acc[0][c] = __builtin_amdgcn_mfma_f32_16x16x32_bf16(a0, bfr, acc[0][c], 0, 0, 0);
            acc[1][c] = __builtin_amdgcn_mfma_f32_16x16x32_bf16(a1, bfr, acc[1][c], 0, 0, 0);
        }
    }

    // epilogue: h (bf16) + fused att dot products
    float attd[8], atts[8];
    #pragma unroll
    for (int c = 0; c < 8; c++) {
        attd[c] = att[c * 16 + col16];
        atts[c] = att[C_OUT + c * 16 + col16];
    }
    #pragma unroll
    for (int rs = 0; rs < 2; rs++) {
        #pragma unroll
        for (int j = 0; j < 4; j++) {
            const int row = rowbase + rs * 16 + kgrp * 4 + j;  // C/D: col=lane&15, row=(lane>>4)*4+j
            const bool ok = (row < N_NODES);
            float pd = 0.f, ps = 0.f;
            #pragma unroll
            for (int c = 0; c < 8; c++) {
                const float hv = acc[rs][c][j];
                pd += hv * attd[c];
                ps += hv * atts[c];
                if (ok) hb[(size_t)row * C_OUT + c * 16 + col16] = f2bf(hv);
            }
            #pragma unroll
            for (int off = 1; off < 16; off <<= 1) {
                pd += __shfl_xor(pd, off);
                ps += __shfl_xor(ps, off);
            }
            if (col16 == 0 && ok) { s_dst[row] = pd; s_src[row] = ps; }
        }
    }
}

// ---------------------------------------------------------------------------
// K2: aggregation by chain-walk. 4 nodes per wave (16 lanes each, one
// uint4/lane = full 256 B bf16 h-row per group). den replicated per group.
// Softmax without max-subtraction (|alpha| small, fp32-safe, ratios exact).
// ---------------------------------------------------------------------------
__global__ __launch_bounds__(256) void aggregate_kernel(
    const ushort* __restrict__ hb, const int* __restrict__ head,
    const int* __restrict__ nxt, const int* __restrict__ ei,
    const float* __restrict__ s_dst, const float* __restrict__ s_src,
    const float* __restrict__ bias, float* __restrict__ out) {
    const int t = threadIdx.x;
    const int wv = t >> 6, lane = t & 63;
    const int sub = lane >> 4, l16 = lane & 15;
    const int node = blockIdx.x * 16 + wv * 4 + sub;   // grid exact: < N_NODES

    const float sd = s_dst[node];
    int e = head[node];
    float den = 0.f;
    float acc[8] = {};
    const uint4* __restrict__ h4 = (const uint4*)hb;

    while (__ballot(e >= 0)) {
        if (e >= 0) {
            const int nx = nxt[e];
            const int s = (e < E_EDGES) ? ei[e] : (e - E_EDGES);
            float a = sd + s_src[s];
            a = (a > 0.f) ? a : NEG_SLOPE * a;
            const float w = __expf(a);
            den += w;
            const uint4 hv = h4[(size_t)s * 16 + l16];
            acc[0] += w * __uint_as_float(hv.x << 16);
            acc[1] += w * __uint_as_float(hv.x & 0xffff0000u);
            acc[2] += w * __uint_as_float(hv.y << 16);
            acc[3] += w * __uint_as_float(hv.y & 0xffff0000u);
            acc[4] += w * __uint_as_float(hv.z << 16);
            acc[5] += w * __uint_as_float(hv.z & 0xffff0000u);
            acc[6] += w * __uint_as_float(hv.w << 16);
            acc[7] += w * __uint_as_float(hv.w & 0xffff0000u);
            e = nx;
        }
    }
    const float inv = 1.f / (den + 1e-16f);
    const float4 b0 = *(const float4*)(bias + l16 * 8);
    const float4 b1 = *(const float4*)(bias + l16 * 8 + 4);
    float4 o0 = make_float4(acc[0] * inv + b0.x, acc[1] * inv + b0.y,
                            acc[2] * inv + b0.z, acc[3] * inv + b0.w);
    float4 o1 = make_float4(acc[4] * inv + b1.x, acc[5] * inv + b1.y,
                            acc[6] * inv + b1.z, acc[7] * inv + b1.w);
    *(float4*)(out + (size_t)node * C_OUT + l16 * 8)     = o0;
    *(float4*)(out + (size_t)node * C_OUT + l16 * 8 + 4) = o1;
}

// ---------------------------------------------------------------------------
extern "C" void kernel_launch(void* const* d_in, const int* in_sizes, int n_in,
                              void* d_out, int out_size, void* d_ws, size_t ws_size,
                              hipStream_t stream) {
    const float* x    = (const float*)d_in[0];
    const int*   ei   = (const int*)d_in[1];
    const float* W    = (const float*)d_in[2];
    const float* att  = (const float*)d_in[3];
    const float* bias = (const float*)d_in[4];
    float* out = (float*)d_out;

    // workspace layout (~17 MB); wt first for 16 B alignment
    ushort* wt    = (ushort*)d_ws;                          // 32768 (64 KB)
    ushort* hbuf  = wt + DIN * C_OUT;                       // N*128 bf16 (12.8 MB)
    float*  s_src = (float*)(hbuf + (size_t)N_NODES * C_OUT);
    float*  s_dst = s_src + N_NODES;
    int*    head  = (int*)(s_dst + N_NODES);                // N
    int*    nxt   = head + N_NODES;                         // ET (3.4 MB)

    wconv_kernel<<<(N_NODES + 255) / 256, 256, 0, stream>>>(W, wt, head);
    gemm_link<<<GEMM_BLOCKS + LINK_BLOCKS, 256, 0, stream>>>(
        x, wt, att, ei, hbuf, s_dst, s_src, head, nxt);
    aggregate_kernel<<<N_NODES / 16, 256, 0, stream>>>(
        hbuf, head, nxt, ei, s_dst, s_src, bias, out);
}